// Round 6
// baseline (3806.925 us; speedup 1.0000x reference)
//
#include <hip/hip_runtime.h>
#include <hip/hip_bf16.h>
#include <stdint.h>

#define TT 1024
#define DD 512
#define HH 512

typedef short bf16x8 __attribute__((ext_vector_type(8)));
typedef float f32x4 __attribute__((ext_vector_type(4)));
typedef unsigned long long u64;
typedef unsigned int u32;
typedef unsigned short u16;

// ---- workspace layout (bytes) ----
#define OFF_WPACK 0ull
#define SZ_WPACK  (32ull*4*4*8*1024)
#define OFF_XS    (OFF_WPACK + SZ_WPACK)
#define SZ_XS     (1024ull*4*2*8*1024)
#define OFF_HB    (OFF_XS + SZ_XS)
#define SZ_HB     (4ull*4*4096*8)

__device__ __forceinline__ u16 f2bf(float f){
  u32 u = __builtin_bit_cast(u32, f);
  u32 r = (u + 0x7fffu + ((u >> 16) & 1u)) >> 16;   // RNE
  return (u16)r;
}

// ---- clear all hbuf tags every launch (no cross-replay state) ----
__global__ void k_clear(u64* hb){
  int id = blockIdx.x * 256 + threadIdx.x;          // 65536
  hb[id] = 0x8000000000000000ull;
}

// ---- pack Wcat=[Wx;Wh] into B-frags (verified r5) ----
__global__ void k_pack_w(const float* __restrict__ Wx, const float* __restrict__ Wh,
                         u16* __restrict__ wp){
  int id = blockIdx.x * 256 + threadIdx.x;          // 262144
  int lane = id & 63;
  int kk = (id >> 6) & 7, G = (id >> 9) & 3, q = (id >> 11) & 3, p = id >> 13;
  int col = G * 512 + p * 16 + (lane & 15);
  int kb  = q * 256 + kk * 32 + (lane >> 4) * 8;
  union { u16 v[8]; uint4 u; } pk;
#pragma unroll
  for (int j = 0; j < 8; ++j){
    int k = kb + j;
    float f = (k < 512) ? Wx[k * 2048 + col] : Wh[(k - 512) * 2048 + col];
    pk.v[j] = f2bf(f);
  }
  long long fid = ((p * 4 + q) * 4 + G) * 8 + kk;
  *((uint4*)wp + fid * 64 + lane) = pk.u;
}

// ---- x -> per-(t,g,q,kk) M=16 A-frags (verified r5) ----
__global__ void k_conv_x(const float* __restrict__ x, uint4* __restrict__ xs){
  int id = blockIdx.x * 256 + threadIdx.x;          // 4,194,304
  int lane = id & 63, kk = (id >> 6) & 7, q = (id >> 9) & 1, g = (id >> 10) & 3, t = id >> 12;
  int row = g * 16 + (lane & 15);
  int k   = q * 256 + kk * 32 + (lane >> 4) * 8;
  const float* src = x + ((long long)row * TT + t) * DD + k;
  union { u16 v[8]; uint4 u; } pk;
#pragma unroll
  for (int j = 0; j < 8; ++j) pk.v[j] = f2bf(src[j]);
  xs[id] = pk.u;
}

// ---- h0 -> tagged words in buf 3, tag = 0xFFFFFFFF (verified r5) ----
__global__ void k_conv_h0(const float* __restrict__ h0, u64* __restrict__ hb){
  int id = blockIdx.x * 256 + threadIdx.x;          // 16384
  int row = id & 15, cp = (id >> 4) & 255, g = id >> 12;
  u32 v0 = f2bf(h0[(g * 16 + row) * HH + 2 * cp]);
  u32 v1 = f2bf(h0[(g * 16 + row) * HH + 2 * cp + 1]);
  hb[((size_t)g * 4 + 3) * 4096 + cp * 16 + row] =
      (0xFFFFFFFFull << 32) | ((u64)v1 << 16) | v0;
}

// ---- persistent scan: 128 wgs (4 groups x 32) x 256 threads ----
// r6: non-divergent reload-all poll + early-issued samples (overlapped with
// gates/publish). All index math identical to verified r5.
__launch_bounds__(256, 1)
__global__ void k_lstm(const float* __restrict__ bias_g, float* __restrict__ out,
                       const u16* __restrict__ wp, const uint4* __restrict__ xs,
                       u64* __restrict__ hbufs)
{
  __shared__ float part[2][4096];    // [buf][q*1024 + G*256 + row*16 + col]

  const int tid  = threadIdx.x;
  const int lane = tid & 63;
  const int q    = tid >> 6;
  const int w    = blockIdx.x;
  const int g    = w >> 5;
  const int p    = w & 31;
  const int khi  = lane >> 4;
  const int llo  = lane & 15;

  // persistent B fragments: 32 frags = 128 VGPRs
  bf16x8 bfrag[4][8];
  {
    const bf16x8* wpf = (const bf16x8*)wp;
#pragma unroll
    for (int G = 0; G < 4; ++G)
#pragma unroll
      for (int kk = 0; kk < 8; ++kk)
        bfrag[G][kk] = wpf[(((p * 4 + q) * 4 + G) * 8 + kk) * 64 + lane];
  }

  // gate mapping
  const int row_g = tid >> 4;
  const int col_g = tid & 15;
  float bia[4];
#pragma unroll
  for (int G = 0; G < 4; ++G) bia[G] = bias_g[G * 512 + p * 16 + col_g];

  float cs = 0.f;

  u64* gb = hbufs + (size_t)g * 4 * 4096;
  const int wbase = (((q & 1) * 128 + khi * 4) * 16) + llo;
  const bool storer = ((col_g & 1) == 0);
  const int swidx = (p * 8 + (col_g >> 1)) * 16 + row_g;
  float* outp = out + ((size_t)(g * 16 + row_g) * TT) * HH + p * 16 + col_g;

  const bool is_h = (q >= 2);

  u64 wv[32];                       // sampled tagged words (h-waves)
  if (is_h){
    const u64* bb = gb + (size_t)3 * 4096;   // t=0 consumer buffer
#pragma unroll
    for (int j = 0; j < 32; ++j){
      int kk = j >> 2, jj = j & 3;
      wv[j] = __hip_atomic_load(bb + wbase + kk * 256 + jj * 16,
                                __ATOMIC_RELAXED, __HIP_MEMORY_SCOPE_AGENT);
    }
  }

  for (int t = 0; t < TT; ++t){
    f32x4 acc[4];
#pragma unroll
    for (int n = 0; n < 4; ++n) acc[n] = (f32x4){0.f, 0.f, 0.f, 0.f};

    if (q < 2){
      // x K-half: plain cached frag loads, never blocks on recurrence
      const uint4* xb = xs + ((((size_t)t * 4 + g) * 2 + q) * 8) * 64 + lane;
#pragma unroll
      for (int kk = 0; kk < 8; ++kk){
        bf16x8 av = __builtin_bit_cast(bf16x8, xb[kk * 64]);
#pragma unroll
        for (int n = 0; n < 4; ++n)
          acc[n] = __builtin_amdgcn_mfma_f32_16x16x32_bf16(av, bfrag[n][kk], acc[n], 0, 0, 0);
      }
    } else {
      // h K-half: check pre-issued samples; tight non-divergent reload-all retry
      const u64* bb = gb + (size_t)((t + 3) & 3) * 4096;
      const u32 tg = (u32)(t - 1);
      for (;;){
        bool ok = true;
#pragma unroll
        for (int j = 0; j < 32; ++j) ok &= ((u32)(wv[j] >> 32) == tg);
        if (__all(ok)) break;
#pragma unroll
        for (int j = 0; j < 32; ++j){
          int kk = j >> 2, jj = j & 3;
          wv[j] = __hip_atomic_load(bb + wbase + kk * 256 + jj * 16,
                                    __ATOMIC_RELAXED, __HIP_MEMORY_SCOPE_AGENT);
        }
      }
      asm volatile("" ::: "memory");
#pragma unroll
      for (int kk = 0; kk < 8; ++kk){
        union { u32 d[4]; bf16x8 v; } af;
#pragma unroll
        for (int jj = 0; jj < 4; ++jj) af.d[jj] = (u32)wv[kk * 4 + jj];
#pragma unroll
        for (int n = 0; n < 4; ++n)
          acc[n] = __builtin_amdgcn_mfma_f32_16x16x32_bf16(af.v, bfrag[n][kk], acc[n], 0, 0, 0);
      }
    }

    // K-partials to double-buffered LDS
    float* pb = &part[t & 1][0];
#pragma unroll
    for (int n = 0; n < 4; ++n)
#pragma unroll
      for (int r = 0; r < 4; ++r)
        pb[q * 1024 + n * 256 + (khi * 4 + r) * 16 + llo] = acc[n][r];
    __syncthreads();   // single barrier per step

    // EARLY-ISSUE samples for step t+1 (consumer buffer = t&3); flight
    // overlaps gate compute + publish. Advisory only — tag-checked above.
    if (is_h && t + 1 < TT){
      const u64* bbn = gb + (size_t)(t & 3) * 4096;
#pragma unroll
      for (int j = 0; j < 32; ++j){
        int kk = j >> 2, jj = j & 3;
        wv[j] = __hip_atomic_load(bbn + wbase + kk * 256 + jj * 16,
                                  __ATOMIC_RELAXED, __HIP_MEMORY_SCOPE_AGENT);
      }
    }

    // gates: 1 h-value per thread
    {
      const float* pr = pb + row_g * 16 + col_g;
      float aG[4];
#pragma unroll
      for (int G = 0; G < 4; ++G)
        aG[G] = pr[G * 256] + pr[1024 + G * 256] + pr[2048 + G * 256]
              + pr[3072 + G * 256] + bia[G];
      float gi = 1.f / (1.f + __expf(-aG[0]));
      float gf = 1.f / (1.f + __expf(-aG[1]));
      float go = 1.f / (1.f + __expf(-aG[2]));
      float e2 = __expf(-2.f * fabsf(aG[3]));
      float gg = __builtin_copysignf((1.f - e2) / (1.f + e2), aG[3]);
      float c  = gf * cs + gi * gg;
      cs = c;
      float ec = __expf(-2.f * fabsf(c));
      float th = __builtin_copysignf((1.f - ec) / (1.f + ec), c);
      float h  = go * th;

      // publish FIRST (critical path), then output store
      u32 hb16 = f2bf(h);
      u32 pv   = __shfl_down(hb16, 1);
      if (storer)
        __hip_atomic_store(gb + (size_t)(t & 3) * 4096 + swidx,
                           ((u64)(u32)t << 32) | ((u64)pv << 16) | hb16,
                           __ATOMIC_RELAXED, __HIP_MEMORY_SCOPE_AGENT);
      outp[(size_t)t * HH] = h;
    }
  }
}

extern "C" void kernel_launch(void* const* d_in, const int* in_sizes, int n_in,
                              void* d_out, int out_size, void* d_ws, size_t ws_size,
                              hipStream_t stream){
  const float* x  = (const float*)d_in[0];
  const float* h0 = (const float*)d_in[1];
  const float* Wx = (const float*)d_in[2];
  const float* Wh = (const float*)d_in[3];
  const float* b  = (const float*)d_in[4];
  float* out = (float*)d_out;

  unsigned char* ws = (unsigned char*)d_ws;
  u16*   wp = (u16*)(ws + OFF_WPACK);
  uint4* xs = (uint4*)(ws + OFF_XS);
  u64*   hb = (u64*)(ws + OFF_HB);

  hipLaunchKernelGGL(k_clear,   dim3(256),   dim3(256), 0, stream, hb);
  hipLaunchKernelGGL(k_pack_w,  dim3(1024),  dim3(256), 0, stream, Wx, Wh, wp);
  hipLaunchKernelGGL(k_conv_x,  dim3(16384), dim3(256), 0, stream, x, xs);
  hipLaunchKernelGGL(k_conv_h0, dim3(64),    dim3(256), 0, stream, h0, hb);
  hipLaunchKernelGGL(k_lstm,    dim3(128),   dim3(256), 0, stream, b, out, wp, xs, hb);
}